// Round 11
// baseline (460.271 us; speedup 1.0000x reference)
//
#include <hip/hip_runtime.h>

// B=8, N=2048, D=F=768. out = softmax((X Wq)(X Wk)^T) (X Wv), fp32 I/O.
// Identity: S[q][k] = sum_d X[q][d] * H[k][d],  H = X * M^T,  M = Wq Wk^T.
// ws: H = fp16(X M^T) [16384][768] | Vt = fp16(X Wv)^T [8][768][2048]
// d_out scratch: Mh fp16 @0 | WvT fp16 @2359296 | Xh fp16 @4194304.
// v15: proj_h/proj_v ported to the m97 structure: 128x128 tile, 4 waves,
//   As/Bs linear [128][64] fp16 (32,768 B LDS, no padding -- global_load_lds
//   writes wave-uniform base + lane*16B), staging via
//   __builtin_amdgcn_global_load_lds(...,16,...) (8 issues/wave/K-step),
//   2 barriers per K-step. fp16 inputs (Xh/Mh/WvT) are the prerequisite:
//   direct-to-LDS staging cannot convert. Expect ~2x on each proj.
// attn byte-identical to v10/v14 (267.7us): 16x16 MFMA, Qtile=64, 1 blk/CU,
//   depth-8 K/V rings. Stall-bound; parked (R2-R9 falsified occupancy/latency/
//   32x32 levers).

typedef __attribute__((ext_vector_type(8))) _Float16 half8;
typedef __attribute__((ext_vector_type(4))) _Float16 half4v;
typedef __attribute__((ext_vector_type(4))) float floatx4;

__device__ __forceinline__ _Float16 f2h(float f) { return (_Float16)f; }
#define MFMA16 __builtin_amdgcn_mfma_f32_16x16x32_f16
#define GLOAD_LDS(g, l) __builtin_amdgcn_global_load_lds( \
    (const __attribute__((address_space(1))) unsigned int*)(g), \
    (__attribute__((address_space(3))) unsigned int*)(l), 16, 0, 0)

// ---------------- Xh = fp16(X), 12.58M elements ----------------
__global__ __launch_bounds__(256) void cast_x_kernel(const float* __restrict__ X,
    _Float16* __restrict__ Xh) {
  size_t idx = (size_t)blockIdx.x * 256 + threadIdx.x;
  for (size_t o8 = idx; o8 < 1572864u; o8 += 524288u) {
    size_t o = o8 * 8;
    float4 a = *(const float4*)(X + o);
    float4 b = *(const float4*)(X + o + 4);
    *(half8*)(Xh + o) = (half8){f2h(a.x), f2h(a.y), f2h(a.z), f2h(a.w),
                                f2h(b.x), f2h(b.y), f2h(b.z), f2h(b.w)};
  }
}

// ---------------- Mh[d][e] = fp16(Wq Wk^T) ----------------
__global__ __launch_bounds__(256) void mm_small_kernel(const float* __restrict__ Wq,
    const float* __restrict__ Wk, _Float16* __restrict__ Mh) {
  __shared__ _Float16 As[128][72];
  __shared__ _Float16 Bs[128][72];
  int bn = blockIdx.x, bm = blockIdx.y;
  int tid = threadIdx.x, lane = tid & 63, wave = tid >> 6;
  int wm = wave >> 1, wn = wave & 1;
  int l15 = lane & 15, quad = lane >> 4;
  floatx4 acc[16];
  for (int i = 0; i < 16; i++) acc[i] = (floatx4){0.f, 0.f, 0.f, 0.f};
  for (int k0 = 0; k0 < 768; k0 += 64) {
    __syncthreads();
    for (int i = 0; i < 8; i++) {
      int f = i * 256 + tid;
      int row = f >> 4, c4 = (f & 15) << 2;
      float4 va = *(const float4*)(Wq + (size_t)(bm * 128 + row) * 768 + k0 + c4);
      *(half4v*)&As[row][c4] = (half4v){f2h(va.x), f2h(va.y), f2h(va.z), f2h(va.w)};
      float4 vb = *(const float4*)(Wk + (size_t)(bn * 128 + row) * 768 + k0 + c4);
      *(half4v*)&Bs[row][c4] = (half4v){f2h(vb.x), f2h(vb.y), f2h(vb.z), f2h(vb.w)};
    }
    __syncthreads();
    for (int kk = 0; kk < 2; kk++) {
      half8 a[4], b[4];
      for (int mt = 0; mt < 4; mt++) a[mt] = *(half8*)&As[wm * 64 + mt * 16 + l15][kk * 32 + quad * 8];
      for (int nt = 0; nt < 4; nt++) b[nt] = *(half8*)&Bs[wn * 64 + nt * 16 + l15][kk * 32 + quad * 8];
      for (int mt = 0; mt < 4; mt++)
        for (int nt = 0; nt < 4; nt++)
          acc[mt * 4 + nt] = MFMA16(a[mt], b[nt], acc[mt * 4 + nt], 0, 0, 0);
    }
  }
  for (int mt = 0; mt < 4; mt++)
    for (int nt = 0; nt < 4; nt++) {
      int e = bn * 128 + wn * 64 + nt * 16 + l15;
      for (int r = 0; r < 4; r++) {
        int d = bm * 128 + wm * 64 + mt * 16 + quad * 4 + r;
        Mh[(size_t)d * 768 + e] = f2h(acc[mt * 4 + nt][r]);
      }
    }
}

// ---------------- WvT[e][d] = Wv[d][e], fp16 ----------------
__global__ void pack_wv_kernel(const float* __restrict__ Wv, _Float16* __restrict__ WvT) {
  __shared__ float tile[32][33];
  int k0 = blockIdx.x * 32;
  int n0 = blockIdx.y * 32;
  int tx = threadIdx.x, ty = threadIdx.y;
  for (int yy = ty; yy < 32; yy += 8)
    tile[yy][tx] = Wv[(size_t)(k0 + yy) * 768 + n0 + tx];
  __syncthreads();
  for (int yy = ty; yy < 32; yy += 8)
    WvT[(size_t)(n0 + yy) * 768 + k0 + tx] = f2h(tile[tx][yy]);
}

// ---------------- H = Xh * Mh^T (m97: global_load_lds, linear LDS, 2 barriers/step) ----------------
__global__ __launch_bounds__(256) void proj_h_kernel(const _Float16* __restrict__ Xh,
    const _Float16* __restrict__ Mh, _Float16* __restrict__ H) {
  __shared__ _Float16 As[128 * 64];   // 16,384 B, linear (gload_lds: no padding)
  __shared__ _Float16 Bs[128 * 64];   // 16,384 B -> total 32,768 B
  int bn = blockIdx.x, bm = blockIdx.y;
  int tid = threadIdx.x, lane = tid & 63, w = tid >> 6;
  int wm = w >> 1, wn = w & 1;
  int l15 = lane & 15, quad = lane >> 4;
  int srow = lane >> 3, scol = (lane & 7) * 8;   // lane's slot within an 8-row chunk
  floatx4 acc[16];
  for (int i = 0; i < 16; i++) acc[i] = (floatx4){0.f, 0.f, 0.f, 0.f};
  for (int t = 0; t < 12; t++) {
    int k0 = t * 64;
    #pragma unroll
    for (int i = 0; i < 4; i++) {
      int c = i * 4 + w;   // chunk 0..15: rows [c*8, c*8+8); wave-uniform LDS base
      GLOAD_LDS(Xh + (size_t)(bm * 128 + c * 8 + srow) * 768 + k0 + scol, &As[c * 512]);
      GLOAD_LDS(Mh + (size_t)(bn * 128 + c * 8 + srow) * 768 + k0 + scol, &Bs[c * 512]);
    }
    __syncthreads();   // compiler drains vmcnt(0) -> tiles resident
    #pragma unroll
    for (int kk = 0; kk < 2; kk++) {
      half8 a[4], b[4];
      #pragma unroll
      for (int mt = 0; mt < 4; mt++) a[mt] = *(half8*)&As[(wm * 64 + mt * 16 + l15) * 64 + kk * 32 + quad * 8];
      #pragma unroll
      for (int nt = 0; nt < 4; nt++) b[nt] = *(half8*)&Bs[(wn * 64 + nt * 16 + l15) * 64 + kk * 32 + quad * 8];
      #pragma unroll
      for (int mt = 0; mt < 4; mt++)
        #pragma unroll
        for (int nt = 0; nt < 4; nt++)
          acc[mt * 4 + nt] = MFMA16(a[mt], b[nt], acc[mt * 4 + nt], 0, 0, 0);
    }
    __syncthreads();   // reads done before next stage overwrites
  }
  for (int mt = 0; mt < 4; mt++)
    for (int nt = 0; nt < 4; nt++) {
      int col = bn * 128 + wn * 64 + nt * 16 + l15;
      for (int r = 0; r < 4; r++) {
        int row = bm * 128 + wm * 64 + mt * 16 + quad * 4 + r;
        H[(size_t)row * 768 + col] = f2h(acc[mt * 4 + nt][r]);
      }
    }
}

// ---------------- Vt[b][d][n] = fp16(Xh * WvT^T)^T (m97 structure) ----------------
__global__ __launch_bounds__(256) void proj_v_kernel(const _Float16* __restrict__ Xh,
    const _Float16* __restrict__ WvT, _Float16* __restrict__ Vt) {
  __shared__ _Float16 As[128 * 64];
  __shared__ _Float16 Bs[128 * 64];
  int bn = blockIdx.x, bm = blockIdx.y;
  int tid = threadIdx.x, lane = tid & 63, w = tid >> 6;
  int wm = w >> 1, wn = w & 1;
  int l15 = lane & 15, quad = lane >> 4;
  int srow = lane >> 3, scol = (lane & 7) * 8;
  floatx4 acc[16];
  for (int i = 0; i < 16; i++) acc[i] = (floatx4){0.f, 0.f, 0.f, 0.f};
  for (int t = 0; t < 12; t++) {
    int k0 = t * 64;
    #pragma unroll
    for (int i = 0; i < 4; i++) {
      int c = i * 4 + w;
      GLOAD_LDS(Xh + (size_t)(bm * 128 + c * 8 + srow) * 768 + k0 + scol, &As[c * 512]);
      GLOAD_LDS(WvT + (size_t)(bn * 128 + c * 8 + srow) * 768 + k0 + scol, &Bs[c * 512]);
    }
    __syncthreads();
    #pragma unroll
    for (int kk = 0; kk < 2; kk++) {
      half8 a[4], b[4];
      #pragma unroll
      for (int mt = 0; mt < 4; mt++) a[mt] = *(half8*)&As[(wm * 64 + mt * 16 + l15) * 64 + kk * 32 + quad * 8];
      #pragma unroll
      for (int nt = 0; nt < 4; nt++) b[nt] = *(half8*)&Bs[(wn * 64 + nt * 16 + l15) * 64 + kk * 32 + quad * 8];
      #pragma unroll
      for (int mt = 0; mt < 4; mt++)
        #pragma unroll
        for (int nt = 0; nt < 4; nt++)
          acc[mt * 4 + nt] = MFMA16(a[mt], b[nt], acc[mt * 4 + nt], 0, 0, 0);
    }
    __syncthreads();
  }
  for (int mt = 0; mt < 4; mt++)
    for (int nt = 0; nt < 4; nt++) {
      int d = bn * 128 + wn * 64 + nt * 16 + l15;
      int tok0 = bm * 128 + wm * 64 + mt * 16 + quad * 4;
      int bb = tok0 >> 11, ntok = tok0 & 2047;
      half4v p;
      for (int r = 0; r < 4; r++) p[r] = f2h(acc[mt * 4 + nt][r]);
      *(half4v*)(Vt + (size_t)(bb * 768 + d) * 2048 + ntok) = p;
    }
}

// ---------------- flash attention v10 (byte-identical): Qtile=64, 1 block/CU, depth-8 rings ----------------
__global__ __launch_bounds__(512, 2) void attn_kernel(const _Float16* __restrict__ H,
    const float* __restrict__ X, const _Float16* __restrict__ Vt, float* __restrict__ out) {
  __shared__ _Float16 Qs[64][776];   // 99,328 B
  __shared__ _Float16 Pl[64][136];   // 17,408 B
  __shared__ float pm[8][64];        //  2,048 B
  __shared__ float psum[8][64];      //  2,048 B
  __shared__ float m_run[64], l_run[64], gmax[64], galpha[64];  // 1,024 B

  int id = blockIdx.x;
  int b = id & 7;            // batch -> XCD
  int q0 = (id >> 3) * 64;   // 32 q-tiles per batch
  int tid = threadIdx.x;
  int lane = tid & 63, w = tid >> 6;   // w in 0..7
  int l15 = lane & 15, quad = lane >> 4;

  if (tid < 64) { m_run[tid] = -1e30f; l_run[tid] = 0.f; }

  floatx4 accO[24];   // [nt][ss]: 6 d-tiles x 4 q-subtiles; wave owns d [w*96,+96)
  for (int i = 0; i < 24; i++) accO[i] = (floatx4){0.f, 0.f, 0.f, 0.f};

  const float*    Xq    = X + (size_t)(b * 2048 + q0) * 768;
  const _Float16* Hbase = H + (size_t)(b * 2048) * 768;
  const _Float16* Vbase = Vt + (size_t)b * 768 * 2048;

  // stage queries: X fp32 -> Qs fp16 (64 x 768), 6144 half8 chunks / 512 thr
  for (int i = 0; i < 12; i++) {
    int f = i * 512 + tid;
    int row = f / 96, c8 = (f % 96) * 8;
    float4 a = *(const float4*)(Xq + (size_t)row * 768 + c8);
    float4 c = *(const float4*)(Xq + (size_t)row * 768 + c8 + 4);
    *(half8*)&Qs[row][c8] = (half8){f2h(a.x), f2h(a.y), f2h(a.z), f2h(a.w),
                                    f2h(c.x), f2h(c.y), f2h(c.z), f2h(c.w)};
  }
  __syncthreads();

  for (int m0 = 0; m0 < 2048; m0 += 128) {
    // ======== S = Q H^T : 64 q-rows x 128 keys; wave w: keys [w*16,+16) ========
    floatx4 sa[4];
    #pragma unroll
    for (int ss = 0; ss < 4; ss++) sa[ss] = (floatx4){0.f, 0.f, 0.f, 0.f};
    const _Float16* Kr = Hbase + (size_t)(m0 + w * 16 + l15) * 768 + quad * 8;
    half8 kpre[8];   // depth-8 ring: ~8 consume-iterations between issue and use
    #pragma unroll
    for (int i = 0; i < 8; i++) kpre[i] = *(const half8*)(Kr + i * 32);
    #pragma unroll
    for (int kb = 0; kb < 24; kb++) {
      half8 kcur = kpre[kb & 7];
      int nxt = (kb + 8 < 24) ? (kb + 8) * 32 : 0;
      kpre[kb & 7] = *(const half8*)(Kr + nxt);
      #pragma unroll
      for (int ss = 0; ss < 4; ss++) {
        half8 qa = *(half8*)&Qs[ss * 16 + l15][kb * 32 + quad * 8];
        sa[ss] = MFMA16(qa, kcur, sa[ss], 0, 0, 0);
      }
    }
    // hoist first PV V loads (wave owns d [w*96,+96)); in flight during softmax
    const _Float16* vb0 = Vbase + (size_t)(w * 96 + l15) * 2048 + m0 + quad * 8;
    half8 vpre[8];   // depth-8 ring
    #pragma unroll
    for (int i = 0; i < 8; i++) {
      int nks = i / 6, nnt = i % 6;
      vpre[i] = *(const half8*)(vb0 + (size_t)nnt * 16 * 2048 + nks * 32);
    }

    // ======== wave-local row max over this wave's 16 keys ========
    float mv[16];
    #pragma unroll
    for (int i = 0; i < 16; i++) mv[i] = sa[i >> 2][i & 3];
    #pragma unroll
    for (int mask = 1; mask <= 8; mask <<= 1)
      #pragma unroll
      for (int i = 0; i < 16; i++) mv[i] = fmaxf(mv[i], __shfl_xor(mv[i], mask));
    if (l15 == 0) {
      #pragma unroll
      for (int i = 0; i < 16; i++) pm[w][(i >> 2) * 16 + quad * 4 + (i & 3)] = mv[i];
    }
    __syncthreads();   // barrier A: pm visible
    if (tid < 64) {    // combine wave maxes once; update m_run (only these threads touch it)
      float mo = m_run[tid];
      float mn = mo;
      #pragma unroll
      for (int w2 = 0; w2 < 8; w2++) mn = fmaxf(mn, pm[w2][tid]);
      gmax[tid] = mn;
      galpha[tid] = __expf(mo - mn);   // first tile: exp(-1e30)=0
      m_run[tid] = mn;
    }
    __syncthreads();   // barrier A2: gmax/galpha visible
    // ======== exp in regs -> Pl (A-layout), row partial sums ========
    float pr[16], al[16];
    #pragma unroll
    for (int i = 0; i < 16; i++) {
      int ss = i >> 2, r = i & 3;
      int row = ss * 16 + quad * 4 + r;
      float mn = gmax[row];
      al[i] = galpha[row];
      float p = __expf(sa[ss][r] - mn);
      pr[i] = p;
      Pl[row][w * 16 + l15] = f2h(p);
    }
    #pragma unroll
    for (int mask = 1; mask <= 8; mask <<= 1)
      #pragma unroll
      for (int i = 0; i < 16; i++) pr[i] += __shfl_xor(pr[i], mask);
    if (l15 == 0) {
      #pragma unroll
      for (int i = 0; i < 16; i++) psum[w][(i >> 2) * 16 + quad * 4 + (i & 3)] = pr[i];
    }
    // rescale O while Pl/psum settle
    #pragma unroll
    for (int nt = 0; nt < 6; nt++)
      #pragma unroll
      for (int i = 0; i < 16; i++)
        accO[nt * 4 + (i >> 2)][i & 3] *= al[i];
    __syncthreads();   // barrier B: Pl + psum visible
    if (tid < 64) {    // fold l_run (parallel over 64 rows)
      float s = 0.f;
      #pragma unroll
      for (int w2 = 0; w2 < 8; w2++) s += psum[w2][tid];
      l_run[tid] = l_run[tid] * galpha[tid] + s;
    }
    // ======== O += P V : 128 keys, 6 d-tiles x 4 q-subtiles ========
    #pragma unroll
    for (int ks = 0; ks < 4; ks++) {
      half8 pa[4];
      #pragma unroll
      for (int ss = 0; ss < 4; ss++) pa[ss] = *(half8*)&Pl[ss * 16 + l15][ks * 32 + quad * 8];
      #pragma unroll
      for (int nt = 0; nt < 6; nt++) {
        int idx = ks * 6 + nt;
        half8 vcur = vpre[idx & 7];
        int nidx = idx + 8;
        int nks = (nidx < 24) ? nidx / 6 : 0;
        int nnt = (nidx < 24) ? nidx % 6 : 0;
        vpre[idx & 7] = *(const half8*)(vb0 + (size_t)nnt * 16 * 2048 + nks * 32);
        #pragma unroll
        for (int ss = 0; ss < 4; ss++)
          accO[nt * 4 + ss] = MFMA16(pa[ss], vcur, accO[nt * 4 + ss], 0, 0, 0);
      }
    }
  }
  __syncthreads();   // l_run final visible
  float il[16];
  #pragma unroll
  for (int i = 0; i < 16; i++) {
    int row = (i >> 2) * 16 + quad * 4 + (i & 3);
    il[i] = 1.f / l_run[row];
  }
  #pragma unroll
  for (int nt = 0; nt < 6; nt++)
    #pragma unroll
    for (int ss = 0; ss < 4; ss++) {
      int d = w * 96 + nt * 16 + l15;
      #pragma unroll
      for (int r = 0; r < 4; r++) {
        int row = q0 + ss * 16 + quad * 4 + r;
        out[(size_t)(b * 2048 + row) * 768 + d] = accO[nt * 4 + ss][r] * il[ss * 4 + r];
      }
    }
}

extern "C" void kernel_launch(void* const* d_in, const int* in_sizes, int n_in,
                              void* d_out, int out_size, void* d_ws, size_t ws_size,
                              hipStream_t stream) {
  (void)in_sizes; (void)n_in; (void)out_size; (void)ws_size;
  const float* X  = (const float*)d_in[0];
  const float* Wq = (const float*)d_in[1];
  const float* Wk = (const float*)d_in[2];
  const float* Wv = (const float*)d_in[3];
  float* out = (float*)d_out;

  char* ws = (char*)d_ws;
  _Float16* H  = (_Float16*)ws;                        // 25,165,824 B
  _Float16* Vt = (_Float16*)(ws + 25165824);           // 25,165,824 B

  // scratch in d_out, consumed before attn writes out:
  _Float16* Mh  = (_Float16*)d_out;                       // 1,179,648 B @ 0
  _Float16* WvT = (_Float16*)((char*)d_out + 2359296);    // 1,179,648 B
  _Float16* Xh  = (_Float16*)((char*)d_out + 4194304);    // 25,165,824 B (ends 29.4 MB)

  cast_x_kernel<<<2048, 256, 0, stream>>>(X, Xh);
  mm_small_kernel<<<dim3(6, 6), 256, 0, stream>>>(Wq, Wk, Mh);
  pack_wv_kernel<<<dim3(24, 24), dim3(32, 8), 0, stream>>>(Wv, WvT);
  proj_h_kernel<<<dim3(6, 128), 256, 0, stream>>>(Xh, Mh, H);
  proj_v_kernel<<<dim3(6, 128), 256, 0, stream>>>(Xh, WvT, Vt);
  attn_kernel<<<256, 512, 0, stream>>>(H, X, Vt, out);
}

// Round 12
// 428.415 us; speedup vs baseline: 1.0744x; 1.0744x over previous
//
#include <hip/hip_runtime.h>

// B=8, N=2048, D=F=768. out = softmax((X Wq)(X Wk)^T) (X Wv), fp32 I/O.
// Identity: S[q][k] = sum_d X[q][d] * H[k][d],  H = X * M^T,  M = Wq Wk^T.
// ws: H = fp16(X M^T) [16384][768] | Vt = fp16(X Wv)^T [8][768][2048]
// d_out scratch: Mh fp16 @0 | WvT fp16 @2359296 | Xh fp16 @4194304.
// v16: 3 dispatches.
//   prep = cast_x (blocks 0..2047) U pack_wv (2048..2623) U mm_small (2624..2659)
//     -- the three are mutually independent; fusing fills the CUs mm_small's
//     36-block launch left idle and removes 2 launch gaps.
//   proj = proj_h (bn 0..5) U proj_v (bn 6..11), dim3(12,128); v14's reg-staged
//     issue-early single-buffer structure (measured best: 178us prologue; v15's
//     same-step global_load_lds drain regressed to 192us -- reverted).
//   attn = v10 byte-identical (267.7us; stall-bound, parked R2-R9).

typedef __attribute__((ext_vector_type(8))) _Float16 half8;
typedef __attribute__((ext_vector_type(4))) _Float16 half4v;
typedef __attribute__((ext_vector_type(4))) float floatx4;

__device__ __forceinline__ _Float16 f2h(float f) { return (_Float16)f; }
#define MFMA16 __builtin_amdgcn_mfma_f32_16x16x32_f16

// ---------------- prep: cast_x U pack_wv U mm_small ----------------
__global__ __launch_bounds__(256) void prep_kernel(const float* __restrict__ X,
    const float* __restrict__ Wq, const float* __restrict__ Wk,
    const float* __restrict__ Wv, _Float16* __restrict__ Xh,
    _Float16* __restrict__ Mh, _Float16* __restrict__ WvT) {
  __shared__ _Float16 As[128][72];
  __shared__ _Float16 Bs[128][72];
  __shared__ float tileF[32][33];
  int id = blockIdx.x;
  int tid = threadIdx.x;
  if (id < 2048) {
    // ---- cast_x: Xh = fp16(X), grid-stride over 1,572,864 half8 chunks ----
    size_t idx = (size_t)id * 256 + tid;
    for (size_t o8 = idx; o8 < 1572864u; o8 += 524288u) {
      size_t o = o8 * 8;
      float4 a = *(const float4*)(X + o);
      float4 b = *(const float4*)(X + o + 4);
      *(half8*)(Xh + o) = (half8){f2h(a.x), f2h(a.y), f2h(a.z), f2h(a.w),
                                  f2h(b.x), f2h(b.y), f2h(b.z), f2h(b.w)};
    }
  } else if (id < 2624) {
    // ---- pack_wv: WvT[e][d] = fp16(Wv[d][e]) ----
    int pid = id - 2048;            // 0..575 = 24x24 tiles
    int k0 = (pid % 24) * 32, n0 = (pid / 24) * 32;
    int tx = tid & 31, ty = tid >> 5;
    for (int yy = ty; yy < 32; yy += 8)
      tileF[yy][tx] = Wv[(size_t)(k0 + yy) * 768 + n0 + tx];
    __syncthreads();
    for (int yy = ty; yy < 32; yy += 8)
      WvT[(size_t)(n0 + yy) * 768 + k0 + tx] = f2h(tileF[tx][yy]);
  } else {
    // ---- mm_small: Mh[d][e] = fp16(Wq Wk^T) ----
    int pid = id - 2624;            // 0..35 = 6x6 tiles
    int bn = pid % 6, bm = pid / 6;
    int lane = tid & 63, wave = tid >> 6;
    int wm = wave >> 1, wn = wave & 1;
    int l15 = lane & 15, quad = lane >> 4;
    floatx4 acc[16];
    for (int i = 0; i < 16; i++) acc[i] = (floatx4){0.f, 0.f, 0.f, 0.f};
    for (int k0 = 0; k0 < 768; k0 += 64) {
      __syncthreads();
      for (int i = 0; i < 8; i++) {
        int f = i * 256 + tid;
        int row = f >> 4, c4 = (f & 15) << 2;
        float4 va = *(const float4*)(Wq + (size_t)(bm * 128 + row) * 768 + k0 + c4);
        *(half4v*)&As[row][c4] = (half4v){f2h(va.x), f2h(va.y), f2h(va.z), f2h(va.w)};
        float4 vb = *(const float4*)(Wk + (size_t)(bn * 128 + row) * 768 + k0 + c4);
        *(half4v*)&Bs[row][c4] = (half4v){f2h(vb.x), f2h(vb.y), f2h(vb.z), f2h(vb.w)};
      }
      __syncthreads();
      for (int kk = 0; kk < 2; kk++) {
        half8 a[4], b[4];
        for (int mt = 0; mt < 4; mt++) a[mt] = *(half8*)&As[wm * 64 + mt * 16 + l15][kk * 32 + quad * 8];
        for (int nt = 0; nt < 4; nt++) b[nt] = *(half8*)&Bs[wn * 64 + nt * 16 + l15][kk * 32 + quad * 8];
        for (int mt = 0; mt < 4; mt++)
          for (int nt = 0; nt < 4; nt++)
            acc[mt * 4 + nt] = MFMA16(a[mt], b[nt], acc[mt * 4 + nt], 0, 0, 0);
      }
    }
    for (int mt = 0; mt < 4; mt++)
      for (int nt = 0; nt < 4; nt++) {
        int e = bn * 128 + wn * 64 + nt * 16 + l15;
        for (int r = 0; r < 4; r++) {
          int d = bm * 128 + wm * 64 + mt * 16 + quad * 4 + r;
          Mh[(size_t)d * 768 + e] = f2h(acc[mt * 4 + nt][r]);
        }
      }
  }
}

// ---------------- fused proj: H (bn<6) and Vt (bn>=6), v14 structure ----------------
__global__ __launch_bounds__(256) void proj_kernel(const _Float16* __restrict__ Xh,
    const _Float16* __restrict__ Mh, const _Float16* __restrict__ WvT,
    _Float16* __restrict__ H, _Float16* __restrict__ Vt) {
  __shared__ _Float16 As[128][72];
  __shared__ _Float16 Bs[128][72];   // 36,864 B -> 4 blocks/CU
  int bnRaw = blockIdx.x, bm = blockIdx.y;
  int isV = bnRaw >= 6;
  int bn = isV ? bnRaw - 6 : bnRaw;
  const _Float16* Bsrc = isV ? WvT : Mh;
  int tid = threadIdx.x, lane = tid & 63, wave = tid >> 6;
  int wm = wave >> 1, wn = wave & 1;
  int l15 = lane & 15, quad = lane >> 4;
  floatx4 acc[16];
  for (int i = 0; i < 16; i++) acc[i] = (floatx4){0.f, 0.f, 0.f, 0.f};
  half8 ra[4], rb[4];
  #pragma unroll
  for (int i = 0; i < 4; i++) {
    int f = i * 256 + tid, row = f >> 3, c8 = (f & 7) << 3;
    ra[i] = *(const half8*)(Xh + (size_t)(bm * 128 + row) * 768 + c8);
    rb[i] = *(const half8*)(Bsrc + (size_t)(bn * 128 + row) * 768 + c8);
  }
  for (int t = 0; t < 12; t++) {
    #pragma unroll
    for (int i = 0; i < 4; i++) {
      int f = i * 256 + tid, row = f >> 3, c8 = (f & 7) << 3;
      *(half8*)&As[row][c8] = ra[i];
      *(half8*)&Bs[row][c8] = rb[i];
    }
    __syncthreads();   // buf ready
    if (t < 11) {      // issue next-tile loads; latency hides under the MFMA block
      int k0 = (t + 1) * 64;
      #pragma unroll
      for (int i = 0; i < 4; i++) {
        int f = i * 256 + tid, row = f >> 3, c8 = (f & 7) << 3;
        ra[i] = *(const half8*)(Xh + (size_t)(bm * 128 + row) * 768 + k0 + c8);
        rb[i] = *(const half8*)(Bsrc + (size_t)(bn * 128 + row) * 768 + k0 + c8);
      }
    }
    #pragma unroll
    for (int kk = 0; kk < 2; kk++) {
      half8 a[4], b[4];
      #pragma unroll
      for (int mt = 0; mt < 4; mt++) a[mt] = *(half8*)&As[wm * 64 + mt * 16 + l15][kk * 32 + quad * 8];
      #pragma unroll
      for (int nt = 0; nt < 4; nt++) b[nt] = *(half8*)&Bs[wn * 64 + nt * 16 + l15][kk * 32 + quad * 8];
      #pragma unroll
      for (int mt = 0; mt < 4; mt++)
        #pragma unroll
        for (int nt = 0; nt < 4; nt++)
          acc[mt * 4 + nt] = MFMA16(a[mt], b[nt], acc[mt * 4 + nt], 0, 0, 0);
    }
    __syncthreads();   // all reads of buf done before next write
  }
  if (!isV) {
    for (int mt = 0; mt < 4; mt++)
      for (int nt = 0; nt < 4; nt++) {
        int col = bn * 128 + wn * 64 + nt * 16 + l15;
        for (int r = 0; r < 4; r++) {
          int row = bm * 128 + wm * 64 + mt * 16 + quad * 4 + r;
          H[(size_t)row * 768 + col] = f2h(acc[mt * 4 + nt][r]);
        }
      }
  } else {
    for (int mt = 0; mt < 4; mt++)
      for (int nt = 0; nt < 4; nt++) {
        int d = bn * 128 + wn * 64 + nt * 16 + l15;
        int tok0 = bm * 128 + wm * 64 + mt * 16 + quad * 4;
        int bb = tok0 >> 11, ntok = tok0 & 2047;
        half4v p;
        for (int r = 0; r < 4; r++) p[r] = f2h(acc[mt * 4 + nt][r]);
        *(half4v*)(Vt + (size_t)(bb * 768 + d) * 2048 + ntok) = p;
      }
  }
}

// ---------------- flash attention v10 (byte-identical): Qtile=64, 1 block/CU, depth-8 rings ----------------
__global__ __launch_bounds__(512, 2) void attn_kernel(const _Float16* __restrict__ H,
    const float* __restrict__ X, const _Float16* __restrict__ Vt, float* __restrict__ out) {
  __shared__ _Float16 Qs[64][776];   // 99,328 B
  __shared__ _Float16 Pl[64][136];   // 17,408 B
  __shared__ float pm[8][64];        //  2,048 B
  __shared__ float psum[8][64];      //  2,048 B
  __shared__ float m_run[64], l_run[64], gmax[64], galpha[64];  // 1,024 B

  int id = blockIdx.x;
  int b = id & 7;            // batch -> XCD
  int q0 = (id >> 3) * 64;   // 32 q-tiles per batch
  int tid = threadIdx.x;
  int lane = tid & 63, w = tid >> 6;   // w in 0..7
  int l15 = lane & 15, quad = lane >> 4;

  if (tid < 64) { m_run[tid] = -1e30f; l_run[tid] = 0.f; }

  floatx4 accO[24];   // [nt][ss]: 6 d-tiles x 4 q-subtiles; wave owns d [w*96,+96)
  for (int i = 0; i < 24; i++) accO[i] = (floatx4){0.f, 0.f, 0.f, 0.f};

  const float*    Xq    = X + (size_t)(b * 2048 + q0) * 768;
  const _Float16* Hbase = H + (size_t)(b * 2048) * 768;
  const _Float16* Vbase = Vt + (size_t)b * 768 * 2048;

  // stage queries: X fp32 -> Qs fp16 (64 x 768), 6144 half8 chunks / 512 thr
  for (int i = 0; i < 12; i++) {
    int f = i * 512 + tid;
    int row = f / 96, c8 = (f % 96) * 8;
    float4 a = *(const float4*)(Xq + (size_t)row * 768 + c8);
    float4 c = *(const float4*)(Xq + (size_t)row * 768 + c8 + 4);
    *(half8*)&Qs[row][c8] = (half8){f2h(a.x), f2h(a.y), f2h(a.z), f2h(a.w),
                                    f2h(c.x), f2h(c.y), f2h(c.z), f2h(c.w)};
  }
  __syncthreads();

  for (int m0 = 0; m0 < 2048; m0 += 128) {
    // ======== S = Q H^T : 64 q-rows x 128 keys; wave w: keys [w*16,+16) ========
    floatx4 sa[4];
    #pragma unroll
    for (int ss = 0; ss < 4; ss++) sa[ss] = (floatx4){0.f, 0.f, 0.f, 0.f};
    const _Float16* Kr = Hbase + (size_t)(m0 + w * 16 + l15) * 768 + quad * 8;
    half8 kpre[8];   // depth-8 ring: ~8 consume-iterations between issue and use
    #pragma unroll
    for (int i = 0; i < 8; i++) kpre[i] = *(const half8*)(Kr + i * 32);
    #pragma unroll
    for (int kb = 0; kb < 24; kb++) {
      half8 kcur = kpre[kb & 7];
      int nxt = (kb + 8 < 24) ? (kb + 8) * 32 : 0;
      kpre[kb & 7] = *(const half8*)(Kr + nxt);
      #pragma unroll
      for (int ss = 0; ss < 4; ss++) {
        half8 qa = *(half8*)&Qs[ss * 16 + l15][kb * 32 + quad * 8];
        sa[ss] = MFMA16(qa, kcur, sa[ss], 0, 0, 0);
      }
    }
    // hoist first PV V loads (wave owns d [w*96,+96)); in flight during softmax
    const _Float16* vb0 = Vbase + (size_t)(w * 96 + l15) * 2048 + m0 + quad * 8;
    half8 vpre[8];   // depth-8 ring
    #pragma unroll
    for (int i = 0; i < 8; i++) {
      int nks = i / 6, nnt = i % 6;
      vpre[i] = *(const half8*)(vb0 + (size_t)nnt * 16 * 2048 + nks * 32);
    }

    // ======== wave-local row max over this wave's 16 keys ========
    float mv[16];
    #pragma unroll
    for (int i = 0; i < 16; i++) mv[i] = sa[i >> 2][i & 3];
    #pragma unroll
    for (int mask = 1; mask <= 8; mask <<= 1)
      #pragma unroll
      for (int i = 0; i < 16; i++) mv[i] = fmaxf(mv[i], __shfl_xor(mv[i], mask));
    if (l15 == 0) {
      #pragma unroll
      for (int i = 0; i < 16; i++) pm[w][(i >> 2) * 16 + quad * 4 + (i & 3)] = mv[i];
    }
    __syncthreads();   // barrier A: pm visible
    if (tid < 64) {    // combine wave maxes once; update m_run (only these threads touch it)
      float mo = m_run[tid];
      float mn = mo;
      #pragma unroll
      for (int w2 = 0; w2 < 8; w2++) mn = fmaxf(mn, pm[w2][tid]);
      gmax[tid] = mn;
      galpha[tid] = __expf(mo - mn);   // first tile: exp(-1e30)=0
      m_run[tid] = mn;
    }
    __syncthreads();   // barrier A2: gmax/galpha visible
    // ======== exp in regs -> Pl (A-layout), row partial sums ========
    float pr[16], al[16];
    #pragma unroll
    for (int i = 0; i < 16; i++) {
      int ss = i >> 2, r = i & 3;
      int row = ss * 16 + quad * 4 + r;
      float mn = gmax[row];
      al[i] = galpha[row];
      float p = __expf(sa[ss][r] - mn);
      pr[i] = p;
      Pl[row][w * 16 + l15] = f2h(p);
    }
    #pragma unroll
    for (int mask = 1; mask <= 8; mask <<= 1)
      #pragma unroll
      for (int i = 0; i < 16; i++) pr[i] += __shfl_xor(pr[i], mask);
    if (l15 == 0) {
      #pragma unroll
      for (int i = 0; i < 16; i++) psum[w][(i >> 2) * 16 + quad * 4 + (i & 3)] = pr[i];
    }
    // rescale O while Pl/psum settle
    #pragma unroll
    for (int nt = 0; nt < 6; nt++)
      #pragma unroll
      for (int i = 0; i < 16; i++)
        accO[nt * 4 + (i >> 2)][i & 3] *= al[i];
    __syncthreads();   // barrier B: Pl + psum visible
    if (tid < 64) {    // fold l_run (parallel over 64 rows)
      float s = 0.f;
      #pragma unroll
      for (int w2 = 0; w2 < 8; w2++) s += psum[w2][tid];
      l_run[tid] = l_run[tid] * galpha[tid] + s;
    }
    // ======== O += P V : 128 keys, 6 d-tiles x 4 q-subtiles ========
    #pragma unroll
    for (int ks = 0; ks < 4; ks++) {
      half8 pa[4];
      #pragma unroll
      for (int ss = 0; ss < 4; ss++) pa[ss] = *(half8*)&Pl[ss * 16 + l15][ks * 32 + quad * 8];
      #pragma unroll
      for (int nt = 0; nt < 6; nt++) {
        int idx = ks * 6 + nt;
        half8 vcur = vpre[idx & 7];
        int nidx = idx + 8;
        int nks = (nidx < 24) ? nidx / 6 : 0;
        int nnt = (nidx < 24) ? nidx % 6 : 0;
        vpre[idx & 7] = *(const half8*)(vb0 + (size_t)nnt * 16 * 2048 + nks * 32);
        #pragma unroll
        for (int ss = 0; ss < 4; ss++)
          accO[nt * 4 + ss] = MFMA16(pa[ss], vcur, accO[nt * 4 + ss], 0, 0, 0);
      }
    }
  }
  __syncthreads();   // l_run final visible
  float il[16];
  #pragma unroll
  for (int i = 0; i < 16; i++) {
    int row = (i >> 2) * 16 + quad * 4 + (i & 3);
    il[i] = 1.f / l_run[row];
  }
  #pragma unroll
  for (int nt = 0; nt < 6; nt++)
    #pragma unroll
    for (int ss = 0; ss < 4; ss++) {
      int d = w * 96 + nt * 16 + l15;
      #pragma unroll
      for (int r = 0; r < 4; r++) {
        int row = q0 + ss * 16 + quad * 4 + r;
        out[(size_t)(b * 2048 + row) * 768 + d] = accO[nt * 4 + ss][r] * il[ss * 4 + r];
      }
    }
}

extern "C" void kernel_launch(void* const* d_in, const int* in_sizes, int n_in,
                              void* d_out, int out_size, void* d_ws, size_t ws_size,
                              hipStream_t stream) {
  (void)in_sizes; (void)n_in; (void)out_size; (void)ws_size;
  const float* X  = (const float*)d_in[0];
  const float* Wq = (const float*)d_in[1];
  const float* Wk = (const float*)d_in[2];
  const float* Wv = (const float*)d_in[3];
  float* out = (float*)d_out;

  char* ws = (char*)d_ws;
  _Float16* H  = (_Float16*)ws;                        // 25,165,824 B
  _Float16* Vt = (_Float16*)(ws + 25165824);           // 25,165,824 B

  // scratch in d_out, consumed before attn writes out:
  _Float16* Mh  = (_Float16*)d_out;                       // 1,179,648 B @ 0
  _Float16* WvT = (_Float16*)((char*)d_out + 2359296);    // 1,179,648 B
  _Float16* Xh  = (_Float16*)((char*)d_out + 4194304);    // 25,165,824 B (ends 29.4 MB)

  prep_kernel<<<2660, 256, 0, stream>>>(X, Wq, Wk, Wv, Xh, Mh, WvT);
  proj_kernel<<<dim3(12, 128), 256, 0, stream>>>(Xh, Mh, WvT, H, Vt);
  attn_kernel<<<256, 512, 0, stream>>>(H, X, Vt, out);
}